// Round 2
// baseline (375.205 us; speedup 1.0000x reference)
//
#include <hip/hip_runtime.h>
#include <stdint.h>

// Problem constants: x[4,64,256,512] fp32, idx[3*256*3*512] i32 (harness converts i64->i32),
// w[64,64,3,3] fp32, bias[64] fp32. out[4,64,256,512] fp32.
#define HW_   131072   // 256*512 = 1<<17
#define W_    512
#define C_    64
#define KDIM  576      // 9 taps * 64 channels

typedef __bf16 bf16_t;
typedef bf16_t bf16x8 __attribute__((ext_vector_type(8)));
typedef float  f32x4_t __attribute__((ext_vector_type(4)));

__device__ __forceinline__ unsigned short f32_to_bf16(float f) {
    union { float f; unsigned u; } v; v.f = f;
    unsigned r = (v.u + 0x7FFFu + ((v.u >> 16) & 1u)) >> 16;  // RNE
    return (unsigned short)r;
}

// ws layout: xt bf16 [B*HW][64] at offset 0 (67,108,864 B); Wfrag bf16 at +XT_BYTES (73,728 B)
#define XT_BYTES   67108864ull
#define WF_BYTES   73728ull

// ---------------------------------------------------------------------------
// Fast path
// ---------------------------------------------------------------------------

// Pack weight[o][c][kh][kw] fp32 -> B-operand fragments, K-order k = t*64 + c, t = kh*3+kw.
// Fragment (kc, nt): lane L holds B[k = kc*32 + (L>>4)*8 + j][n = nt*16 + (L&15)], j=0..7.
__global__ __launch_bounds__(256) void k_prep_w(const float* __restrict__ w,
                                                unsigned short* __restrict__ wfrag) {
    int id = blockIdx.x * 256 + threadIdx.x;   // (kc*4 + nt)*64 + lane, total 18*4*64 = 4608
    if (id >= 18 * 4 * 64) return;
    int lane = id & 63;
    int nt   = (id >> 6) & 3;
    int kc   = id >> 8;
    int n  = nt * 16 + (lane & 15);
    int k0 = kc * 32 + ((lane >> 4) << 3);
    unsigned short tmp[8];
#pragma unroll
    for (int j = 0; j < 8; ++j) {
        int k = k0 + j;
        int t = k >> 6;    // tap 0..8
        int c = k & 63;
        tmp[j] = f32_to_bf16(w[(size_t)n * KDIM + c * 9 + t]);
    }
    uint4 v;
    v.x = tmp[0] | ((unsigned)tmp[1] << 16);
    v.y = tmp[2] | ((unsigned)tmp[3] << 16);
    v.z = tmp[4] | ((unsigned)tmp[5] << 16);
    v.w = tmp[6] | ((unsigned)tmp[7] << 16);
    ((uint4*)wfrag)[id] = v;
}

// Transpose + convert: x[b][c][p] fp32 -> xt[(b*HW + p)][c] bf16 (rows = 128 B, one cache line)
__global__ __launch_bounds__(256) void k_transpose(const float* __restrict__ x,
                                                   unsigned short* __restrict__ xt) {
    int gp = blockIdx.x * 256 + threadIdx.x;      // global (b, p); grid = 4*HW/256 = 2048
    int b = gp >> 17;
    int p = gp & (HW_ - 1);
    const float* xb = x + ((size_t)b * C_) * HW_ + p;
    uint4* dst = (uint4*)(xt + (size_t)gp * C_);
#pragma unroll
    for (int cc = 0; cc < 8; ++cc) {
        unsigned short tmp[8];
#pragma unroll
        for (int j = 0; j < 8; ++j)
            tmp[j] = f32_to_bf16(xb[(size_t)(cc * 8 + j) * HW_]);   // coalesced across lanes (p)
        uint4 v;
        v.x = tmp[0] | ((unsigned)tmp[1] << 16);
        v.y = tmp[2] | ((unsigned)tmp[3] << 16);
        v.z = tmp[4] | ((unsigned)tmp[5] << 16);
        v.w = tmp[6] | ((unsigned)tmp[7] << 16);
        dst[cc] = v;
    }
}

// Gather-GEMM: per wave, M=64 consecutive pixels x N=64 out-channels, K=576.
// A loaded directly from global via gathered row pointers; B from prepacked Wfrag.
__global__ __launch_bounds__(256) void k_gemm(const unsigned short* __restrict__ xt,
                                              const unsigned short* __restrict__ wfrag,
                                              const int* __restrict__ idx,
                                              const float* __restrict__ bias,
                                              float* __restrict__ out) {
    __shared__ unsigned p_lds[4][64][9];   // [wave][pixel][tap], 9216 B

    int tid  = threadIdx.x;
    int wave = tid >> 6;
    int lane = tid & 63;
    int gbase = blockIdx.x * 256 + wave * 64;   // first pixel of this wave (same b for all 64)
    int b = gbase >> 17;

    // Phase 1: lane L loads the 9 gather indices for pixel gbase+L
    {
        int g  = gbase + lane;
        int hw = g & (HW_ - 1);
        int h = hw >> 9, w = hw & (W_ - 1);
        size_t base = (size_t)(3 * h) * (3 * W_) + 3 * w;
#pragma unroll
        for (int th = 0; th < 3; ++th)
#pragma unroll
            for (int tw = 0; tw < 3; ++tw)
                p_lds[wave][lane][th * 3 + tw] = (unsigned)idx[base + (size_t)th * (3 * W_) + tw];
    }
    __syncthreads();

    f32x4_t acc[4][4] = {};       // [msub][nt]
    int quad = lane >> 4;
    int col  = lane & 15;
    const unsigned short* xtb = xt + (((size_t)b) << 17) * C_;

    for (int kc = 0; kc < 18; ++kc) {
        int t = kc >> 1;
        int byteoff = ((kc & 1) << 6) + (quad << 4);   // ((kc&1)*32 + quad*8) bf16 elements

        bf16x8 bfrag[4];
#pragma unroll
        for (int nt = 0; nt < 4; ++nt) {
            const uint4* wp = (const uint4*)(wfrag + ((size_t)((kc * 4 + nt) * 64 + lane) << 3));
            bfrag[nt] = __builtin_bit_cast(bf16x8, *wp);
        }
        bf16x8 afrag[4];
#pragma unroll
        for (int ms = 0; ms < 4; ++ms) {
            unsigned p = p_lds[wave][ms * 16 + col][t];
            const uint4* ap = (const uint4*)((const char*)(xtb + (size_t)p * C_) + byteoff);
            afrag[ms] = __builtin_bit_cast(bf16x8, *ap);
        }
#pragma unroll
        for (int ms = 0; ms < 4; ++ms)
#pragma unroll
            for (int nt = 0; nt < 4; ++nt)
                acc[ms][nt] = __builtin_amdgcn_mfma_f32_16x16x32_bf16(
                    afrag[ms], bfrag[nt], acc[ms][nt], 0, 0, 0);
    }

    // Epilogue: C/D layout col=lane&15 (n), row=quad*4+reg (m). 4 consecutive m = f32x4 store.
#pragma unroll
    for (int nt = 0; nt < 4; ++nt) {
        int o = nt * 16 + col;
        float bv = bias[o];
#pragma unroll
        for (int ms = 0; ms < 4; ++ms) {
            int m0 = ms * 16 + quad * 4;
            int hw0 = (gbase + m0) & (HW_ - 1);
            f32x4_t v = acc[ms][nt];
            v.x += bv; v.y += bv; v.z += bv; v.w += bv;
            *(f32x4_t*)(out + (((size_t)(b * 64 + o)) << 17) + hw0) = v;
        }
    }
}

// ---------------------------------------------------------------------------
// Fallback path (ws too small): direct fp32, slow but correct, no workspace.
// One thread per output element.
// ---------------------------------------------------------------------------
__global__ __launch_bounds__(256) void k_fallback(const float* __restrict__ x,
                                                  const int* __restrict__ idx,
                                                  const float* __restrict__ w,
                                                  const float* __restrict__ bias,
                                                  float* __restrict__ out) {
    size_t g = (size_t)blockIdx.x * 256 + threadIdx.x;   // (b*64+o)*HW + hw
    int hw = (int)(g & (HW_ - 1));
    int o  = (int)((g >> 17) & 63);
    int b  = (int)(g >> 23);
    int h = hw >> 9, ww = hw & (W_ - 1);
    size_t ibase = (size_t)(3 * h) * (3 * W_) + 3 * ww;
    int p[9];
#pragma unroll
    for (int th = 0; th < 3; ++th)
#pragma unroll
        for (int tw = 0; tw < 3; ++tw)
            p[th * 3 + tw] = idx[ibase + (size_t)th * (3 * W_) + tw];
    const float* xb = x + (size_t)b * C_ * HW_;
    const float* wo = w + (size_t)o * KDIM;
    float acc = bias[o];
    for (int c = 0; c < C_; ++c) {
        const float* xc = xb + (size_t)c * HW_;
        const float* wc = wo + c * 9;
#pragma unroll
        for (int t = 0; t < 9; ++t)
            acc += xc[p[t]] * wc[t];
    }
    out[g] = acc;
}

extern "C" void kernel_launch(void* const* d_in, const int* in_sizes, int n_in,
                              void* d_out, int out_size, void* d_ws, size_t ws_size,
                              hipStream_t stream) {
    const float* x    = (const float*)d_in[0];
    const int*   idx  = (const int*)d_in[1];     // harness delivers integer inputs as int32
    const float* w    = (const float*)d_in[2];
    const float* bias = (const float*)d_in[3];
    float* out = (float*)d_out;

    if (ws_size >= XT_BYTES + WF_BYTES) {
        unsigned short* xt    = (unsigned short*)d_ws;
        unsigned short* wfrag = (unsigned short*)((char*)d_ws + XT_BYTES);
        k_prep_w   <<<18,   256, 0, stream>>>(w, wfrag);
        k_transpose<<<2048, 256, 0, stream>>>(x, xt);
        k_gemm     <<<2048, 256, 0, stream>>>(xt, wfrag, idx, bias, out);
    } else {
        // 33,554,432 outputs / 256 = 131072 blocks
        k_fallback<<<131072, 256, 0, stream>>>(x, idx, w, bias, out);
    }
}

// Round 3
// 354.789 us; speedup vs baseline: 1.0575x; 1.0575x over previous
//
#include <hip/hip_runtime.h>
#include <stdint.h>

// Problem constants: x[4,64,256,512] fp32, idx[3*256*3*512] i32 (harness converts i64->i32),
// w[64,64,3,3] fp32, bias[64] fp32. out[4,64,256,512] fp32.
#define HW_   131072   // 256*512 = 1<<17
#define W_    512
#define C_    64
#define KDIM  576      // 9 taps * 64 channels

typedef __bf16 bf16_t;
typedef bf16_t bf16x8 __attribute__((ext_vector_type(8)));
typedef float  f32x4_t __attribute__((ext_vector_type(4)));

__device__ __forceinline__ unsigned short f32_to_bf16(float f) {
    union { float f; unsigned u; } v; v.f = f;
    unsigned r = (v.u + 0x7FFFu + ((v.u >> 16) & 1u)) >> 16;  // RNE
    return (unsigned short)r;
}

// ws layout: xt bf16 [B*HW][64] at offset 0 (67,108,864 B); Wfrag bf16 at +XT_BYTES (73,728 B)
#define XT_BYTES   67108864ull
#define WF_BYTES   73728ull

// ---------------------------------------------------------------------------
// Pack weight[o][c][kh][kw] fp32 -> B-operand fragments, K-order k = t*64 + c, t = kh*3+kw.
// Fragment (kc, nt): lane L holds B[k = kc*32 + (L>>4)*8 + j][n = nt*16 + (L&15)], j=0..7.
// ---------------------------------------------------------------------------
__global__ __launch_bounds__(256) void k_prep_w(const float* __restrict__ w,
                                                unsigned short* __restrict__ wfrag) {
    int id = blockIdx.x * 256 + threadIdx.x;   // (kc*4 + nt)*64 + lane, total 18*4*64 = 4608
    if (id >= 18 * 4 * 64) return;
    int lane = id & 63;
    int nt   = (id >> 6) & 3;
    int kc   = id >> 8;
    int n  = nt * 16 + (lane & 15);
    int k0 = kc * 32 + ((lane >> 4) << 3);
    unsigned short tmp[8];
#pragma unroll
    for (int j = 0; j < 8; ++j) {
        int k = k0 + j;
        int t = k >> 6;    // tap 0..8
        int c = k & 63;
        tmp[j] = f32_to_bf16(w[(size_t)n * KDIM + c * 9 + t]);
    }
    uint4 v;
    v.x = tmp[0] | ((unsigned)tmp[1] << 16);
    v.y = tmp[2] | ((unsigned)tmp[3] << 16);
    v.z = tmp[4] | ((unsigned)tmp[5] << 16);
    v.w = tmp[6] | ((unsigned)tmp[7] << 16);
    ((uint4*)wfrag)[id] = v;
}

// ---------------------------------------------------------------------------
// Transpose + convert via LDS: x[b][c][p] fp32 -> xt[(b*HW+p)][c] bf16.
// Phase 1: coalesced dword reads (256 consecutive p per instr), pack bf16 pairs into LDS.
// Phase 2: coalesced row-major stores (lane-contiguous 16 B chunks -> 1 KiB/instr).
// ---------------------------------------------------------------------------
__global__ __launch_bounds__(256) void k_transpose(const float* __restrict__ x,
                                                   unsigned short* __restrict__ xt) {
    __shared__ unsigned short tile[256][68];   // pad 68: 2-way bank alias on writes (free)
    int t  = threadIdx.x;
    int gp0 = blockIdx.x * 256;                // grid = 2048
    int b  = gp0 >> 17;
    int p0 = gp0 & (HW_ - 1);
    const float* xb = x + ((size_t)b * C_) * HW_ + p0 + t;
#pragma unroll
    for (int c = 0; c < 64; c += 2) {
        unsigned a0 = f32_to_bf16(xb[(size_t)c << 17]);
        unsigned a1 = f32_to_bf16(xb[(size_t)(c + 1) << 17]);
        *(unsigned*)&tile[t][c] = a0 | (a1 << 16);
    }
    __syncthreads();
    unsigned short* dst = xt + (size_t)gp0 * C_;
#pragma unroll
    for (int it = 0; it < 8; ++it) {
        int cid = it * 256 + t;        // 2048 chunks of 16 B
        int px  = cid >> 3;
        int ch  = cid & 7;
        uint4 v;
        v.x = *(unsigned*)&tile[px][ch * 8 + 0];
        v.y = *(unsigned*)&tile[px][ch * 8 + 2];
        v.z = *(unsigned*)&tile[px][ch * 8 + 4];
        v.w = *(unsigned*)&tile[px][ch * 8 + 6];
        ((uint4*)(dst + (size_t)px * C_))[ch] = v;   // lane-contiguous across the wave
    }
}

// ---------------------------------------------------------------------------
// Gather-GEMM, software-pipelined. Per wave: M=32 pixels x N=64, K=576.
// 18 half-K steps (s = kc), 3-stage rotating register buffers: loads for step
// s+3 are issued behind the MFMAs of step s. Gather indices live in registers.
// Grid 4096 x 256 threads; block covers 128 consecutive pixels (same batch).
// ---------------------------------------------------------------------------
__global__ __launch_bounds__(256) void k_gemm(const unsigned short* __restrict__ xt,
                                              const unsigned short* __restrict__ wfrag,
                                              const int* __restrict__ idx,
                                              const float* __restrict__ bias,
                                              float* __restrict__ out) {
    __shared__ unsigned p_lds[128][9];   // 4608 B

    int tid  = threadIdx.x;
    int wave = tid >> 6;
    int lane = tid & 63;
    int gbase = blockIdx.x * 128;        // first pixel of block; same b for all 128
    int b = gbase >> 17;

    // Stage gather indices: 2 threads per pixel (128 px * 9 taps)
    {
        int px   = tid >> 1;
        int half = tid & 1;
        int g  = gbase + px;
        int hw = g & (HW_ - 1);
        int h = hw >> 9, w = hw & (W_ - 1);
        size_t base = (size_t)(3 * h) * (3 * W_) + 3 * w;
        if (half == 0) {
#pragma unroll
            for (int t = 0; t < 5; ++t)
                p_lds[px][t] = (unsigned)idx[base + (size_t)(t / 3) * (3 * W_) + (t % 3)];
        } else {
#pragma unroll
            for (int t = 5; t < 9; ++t)
                p_lds[px][t] = (unsigned)idx[base + (size_t)(t / 3) * (3 * W_) + (t % 3)];
        }
    }
    __syncthreads();

    int quad = lane >> 4;
    int col  = lane & 15;
    int pxw  = wave * 32;

    // Hoist this lane's 18 gather indices into registers
    unsigned p_reg[9][2];
#pragma unroll
    for (int t = 0; t < 9; ++t) {
        p_reg[t][0] = p_lds[pxw + col][t];
        p_reg[t][1] = p_lds[pxw + 16 + col][t];
    }

    const unsigned short* xtb = xt + (((size_t)b) << 17) * C_;
    const uint4* wf = (const uint4*)wfrag;

    f32x4_t acc[2][4] = {};
    bf16x8 Abuf[3][2];
    bf16x8 Bbuf[3][4];

    // load step s (= kc): A frag per ms at row p_reg[s>>1][ms], byte off (s&1)*64 + quad*16
    // B frags (s*4+nt)*64 + lane
#define ISSUE(s, slot)                                                              \
    {                                                                               \
        const int t_ = (s) >> 1, h_ = (s) & 1;                                      \
        _Pragma("unroll")                                                           \
        for (int ms = 0; ms < 2; ++ms) {                                            \
            const uint4* ap = (const uint4*)((const char*)xtb +                     \
                ((size_t)p_reg[t_][ms] << 7) + (h_ << 6) + (quad << 4));            \
            Abuf[slot][ms] = __builtin_bit_cast(bf16x8, *ap);                       \
        }                                                                           \
        _Pragma("unroll")                                                           \
        for (int nt = 0; nt < 4; ++nt)                                              \
            Bbuf[slot][nt] = __builtin_bit_cast(bf16x8, wf[((s) * 4 + nt) * 64 + lane]); \
    }

    ISSUE(0, 0)
    ISSUE(1, 1)
    ISSUE(2, 2)
#pragma unroll
    for (int s = 0; s < 18; ++s) {
        const int slot = s % 3;
#pragma unroll
        for (int ms = 0; ms < 2; ++ms)
#pragma unroll
            for (int nt = 0; nt < 4; ++nt)
                acc[ms][nt] = __builtin_amdgcn_mfma_f32_16x16x32_bf16(
                    Abuf[slot][ms], Bbuf[slot][nt], acc[ms][nt], 0, 0, 0);
        if (s + 3 < 18) ISSUE(s + 3, slot)
    }
#undef ISSUE

    // Epilogue: C/D layout col=lane&15 (n), row=quad*4+reg (m). f32x4 stores.
#pragma unroll
    for (int nt = 0; nt < 4; ++nt) {
        int o = nt * 16 + col;
        float bv = bias[o];
#pragma unroll
        for (int ms = 0; ms < 2; ++ms) {
            int m0 = ms * 16 + quad * 4;
            int hw0 = (gbase + pxw + m0) & (HW_ - 1);
            f32x4_t v = acc[ms][nt];
            v.x += bv; v.y += bv; v.z += bv; v.w += bv;
            *(f32x4_t*)(out + (((size_t)(b * 64 + o)) << 17) + hw0) = v;
        }
    }
}

// ---------------------------------------------------------------------------
// Fallback path (ws too small): direct fp32, slow but correct, no workspace.
// ---------------------------------------------------------------------------
__global__ __launch_bounds__(256) void k_fallback(const float* __restrict__ x,
                                                  const int* __restrict__ idx,
                                                  const float* __restrict__ w,
                                                  const float* __restrict__ bias,
                                                  float* __restrict__ out) {
    size_t g = (size_t)blockIdx.x * 256 + threadIdx.x;   // (b*64+o)*HW + hw
    int hw = (int)(g & (HW_ - 1));
    int o  = (int)((g >> 17) & 63);
    int b  = (int)(g >> 23);
    int h = hw >> 9, ww = hw & (W_ - 1);
    size_t ibase = (size_t)(3 * h) * (3 * W_) + 3 * ww;
    int p[9];
#pragma unroll
    for (int th = 0; th < 3; ++th)
#pragma unroll
        for (int tw = 0; tw < 3; ++tw)
            p[th * 3 + tw] = idx[ibase + (size_t)th * (3 * W_) + tw];
    const float* xb = x + (size_t)b * C_ * HW_;
    const float* wo = w + (size_t)o * KDIM;
    float acc = bias[o];
    for (int c = 0; c < C_; ++c) {
        const float* xc = xb + (size_t)c * HW_;
        const float* wc = wo + c * 9;
#pragma unroll
        for (int t = 0; t < 9; ++t)
            acc += xc[p[t]] * wc[t];
    }
    out[g] = acc;
}

extern "C" void kernel_launch(void* const* d_in, const int* in_sizes, int n_in,
                              void* d_out, int out_size, void* d_ws, size_t ws_size,
                              hipStream_t stream) {
    const float* x    = (const float*)d_in[0];
    const int*   idx  = (const int*)d_in[1];     // harness delivers integer inputs as int32
    const float* w    = (const float*)d_in[2];
    const float* bias = (const float*)d_in[3];
    float* out = (float*)d_out;

    if (ws_size >= XT_BYTES + WF_BYTES) {
        unsigned short* xt    = (unsigned short*)d_ws;
        unsigned short* wfrag = (unsigned short*)((char*)d_ws + XT_BYTES);
        k_prep_w   <<<18,   256, 0, stream>>>(w, wfrag);
        k_transpose<<<2048, 256, 0, stream>>>(x, xt);
        k_gemm     <<<4096, 256, 0, stream>>>(xt, wfrag, idx, bias, out);
    } else {
        k_fallback<<<131072, 256, 0, stream>>>(x, idx, w, bias, out);
    }
}